// Round 1
// baseline (547.993 us; speedup 1.0000x reference)
//
#include <hip/hip_runtime.h>
#include <cstdint>
#include <cstddef>

using short8  = __attribute__((ext_vector_type(8))) short;
using floatx4 = __attribute__((ext_vector_type(4))) float;

#define DEV __device__ __forceinline__

DEV float u2f(unsigned short u){
  union { unsigned int i; float f; } c; c.i = ((unsigned int)u) << 16; return c.f;
}
DEV unsigned short f2u(float f){
  union { float f; unsigned int i; } c; c.f = f;
  unsigned int i = c.i;
  i += 0x7fffu + ((i >> 16) & 1u);   // RNE to bf16 (finite values only here)
  return (unsigned short)(i >> 16);
}
DEV float sigmoidf_(float x){ return 1.0f / (1.0f + __expf(-x)); }
DEV float siluf_(float x){ return x / (1.0f + __expf(-x)); }

// async global->LDS, 16 B per lane; LDS dest must be wave-uniform base + lane*16
#define ASYNC_LD16(g, l) __builtin_amdgcn_global_load_lds( \
    (const __attribute__((address_space(1))) unsigned int*)(g), \
    (__attribute__((address_space(3))) unsigned int*)(l), 16, 0, 0)

// problem-fixed sizes: T=2048 S=2048 B=4 E=1024 Z=128
constexpr float SCALING = 0.088388347648318447f; // 128^-0.5

// ---------------------------------------------------------------- casts
// blocks [0,8192): query row copy -> qbf (T*B,E)
// blocks [8192,16384): key row m=(s,b) -> kbr[b][s][e] (de-interleave batch)
__global__ __launch_bounds__(256) void cast_act(
    const float* __restrict__ q, const float* __restrict__ k,
    unsigned short* __restrict__ qo, unsigned short* __restrict__ ko)
{
  const int bid = blockIdx.x;
  const int e = threadIdx.x * 4;
  const float* src; unsigned short* dst;
  if (bid < 8192) {
    src = q + (long long)bid * 1024;
    dst = qo + (long long)bid * 1024;
  } else {
    const int m = bid - 8192;
    const int s = m >> 2, b = m & 3;
    src = k + (long long)m * 1024;
    dst = ko + ((long long)b * 2048 + s) * 1024;
  }
  const float4 v = *(const float4*)(src + e);
  ushort4 o; o.x=f2u(v.x); o.y=f2u(v.y); o.z=f2u(v.z); o.w=f2u(v.w);
  *(ushort4*)(dst + e) = o;
}

// weight casts: rows [0,2176) Wq, [2176,2304) Wk, [2304,3328) Wv, [3328,4352) Wh
__global__ __launch_bounds__(256) void cast_w(
    const float* __restrict__ Wq, const float* __restrict__ Wk,
    const float* __restrict__ Wv, const float* __restrict__ Wh,
    unsigned short* __restrict__ oq, unsigned short* __restrict__ ok,
    unsigned short* __restrict__ ov, unsigned short* __restrict__ oh)
{
  const int bid = blockIdx.x;
  const int e = threadIdx.x * 4;
  const float* src; unsigned short* dst;
  if (bid < 2176)      { src = Wq + (long long)bid * 1024;        dst = oq + (long long)bid * 1024; }
  else if (bid < 2304) { src = Wk + (long long)(bid-2176) * 1024; dst = ok + (long long)(bid-2176) * 1024; }
  else if (bid < 3328) { src = Wv + (long long)(bid-2304) * 1024; dst = ov + (long long)(bid-2304) * 1024; }
  else                 { src = Wh + (long long)(bid-3328) * 1024; dst = oh + (long long)(bid-3328) * 1024; }
  const float4 v = *(const float4*)(src + e);
  ushort4 o; o.x=f2u(v.x); o.y=f2u(v.y); o.z=f2u(v.z); o.w=f2u(v.w);
  *(ushort4*)(dst + e) = o;
}

// ---------------------------------------------------------------- GEMM-BT
// C[M,N] = A[M,K] * B[N,K]^T, bf16 in, fp32 acc.
// R8: 256x128 tile, BK=64, 512 threads (8 waves 4Mx2N, per-wave 64x64 = 4x4
// fragments of 16x16x32 MFMA — same verified acc layout as before).
// TRIPLE-buffered LDS (3 x 48 KB = 144 KB) with counted-vmcnt pipeline
// (T3+T4): tile t's 6 global_load_lds are issued during tile t-2; the
// per-tile boundary wait is s_waitcnt vmcnt(6) (tile t+1's 6 loads stay in
// flight — never drained to 0 in the main loop; only the last tile drains).
// Each K-tile = 2 phases of {stage 3 loads; ds_read; s_barrier; setprio(1);
// 16 MFMA; setprio(0); s_barrier} (T5 setprio gated on phase split).
// Staging keeps the proven XOR-swizzled unpadded LDS layout (0 conflicts):
// chunk c: row rr=c>>3, LDS slot c&7 holds global chunk (c&7)^(rr&7);
// read side slot = chunk ^ (row&7), row&7 == lr&7.
// Grids at BN=128: <0> 32x17=544, <2>/<4>/<5> 256 blocks, 1 block/CU.
// EPI: 0 = Wq proj: u=sigmoid (bf16, via f0 reinterpret), r=silu, q=silu*g+b
//      1 = k proj
//      2 = v proj SWAPPED (A=Wv, B=kbr): gm=e, gn=(b,s) -> vT coalesced
//      3 = exp epilogue: P~ = exp(v*SCALING) bf16 + atomic fp32 rowsum (f0)
//      4 = PV: h = acc/rowsum, out = h*r (bf16)
//      5 = Wh proj -> out = q + u*(tanh(.)-q)  (fp32; u bf16 via rmul)
template<int EPI>
__global__ __launch_bounds__(512, 2)
void gemm_bt(const unsigned short* __restrict__ A, long long bsA, int lda,
             const unsigned short* __restrict__ Bm, long long bsB, int ldb,
             int K,
             const float* __restrict__ bias,
             const float* __restrict__ gam,
             const float* __restrict__ bet,
             float* __restrict__ f0,
             unsigned short* __restrict__ b0,
             unsigned short* __restrict__ b1,
             const unsigned short* __restrict__ rmul,
             const float* __restrict__ qin)
{
  __shared__ __align__(16) unsigned short As[3][256][64];  // 96 KB
  __shared__ __align__(16) unsigned short Bs[3][128][64];  // 48 KB

  const int tid = threadIdx.x;
  const int bm = blockIdx.x, bn = blockIdx.y, bz = blockIdx.z;
  const unsigned short* Ag = A  + (long long)bz * bsA;
  const unsigned short* Bg = Bm + (long long)bz * bsB;
  const int row0 = bm * 256;
  const int col0 = bn * 128;

  const int lane = tid & 63;
  const int wv   = tid >> 6;
  const int wmr  = (wv & 3) * 64;   // wave M offset in [0,256)
  const int wnc  = (wv >> 2) * 64;  // wave N offset in [0,128)
  const int lr   = lane & 15;   // fragment m/n index
  const int lq   = lane >> 4;   // quad: k = lq*8.., C row = lq*4+reg
  const int r7   = lr & 7;      // read-side swizzle key

  // staging addresses: A tile = 4 instrs x 512 lanes x 16B, B tile = 2 instrs
  const unsigned short* gA[4]; const unsigned short* gB[2];
  unsigned short* lA[4]; unsigned short* lB[2];
  #pragma unroll
  for (int i = 0; i < 4; i++) {
    const int c  = tid + i * 512;
    const int rr = c >> 3;
    const int gc = (c & 7) ^ (rr & 7);
    gA[i] = Ag + (long long)(row0 + rr) * lda + gc * 8;
    lA[i] = &As[0][0][0] + c * 8;
  }
  #pragma unroll
  for (int i = 0; i < 2; i++) {
    const int c  = tid + i * 512;
    const int rr = c >> 3;
    const int gc = (c & 7) ^ (rr & 7);
    gB[i] = Bg + (long long)(col0 + rr) * ldb + gc * 8;
    lB[i] = &Bs[0][0][0] + c * 8;
  }

  floatx4 acc[4][4];
  const floatx4 zero = {0.f, 0.f, 0.f, 0.f};
  #pragma unroll
  for (int i = 0; i < 4; i++)
    #pragma unroll
    for (int j = 0; j < 4; j++) acc[i][j] = zero;

  const int NT = K >> 6;  // all K in {128,1024,2048} -> NT >= 2

  // prologue: stage tile 0 -> buf0, tile 1 -> buf1 (12 loads), then
  // guarantee tile 0 landed for all waves: vmcnt(6) + barrier.
  #pragma unroll
  for (int i = 0; i < 4; i++) ASYNC_LD16(gA[i], lA[i]);
  #pragma unroll
  for (int i = 0; i < 2; i++) ASYNC_LD16(gB[i], lB[i]);
  #pragma unroll
  for (int i = 0; i < 4; i++) ASYNC_LD16(gA[i] + 64, lA[i] + 16384);
  #pragma unroll
  for (int i = 0; i < 2; i++) ASYNC_LD16(gB[i] + 64, lB[i] + 8192);
  asm volatile("s_waitcnt vmcnt(6)" ::: "memory");
  __builtin_amdgcn_s_barrier();

  int cur = 0;
  for (int t = 0; t < NT; ++t) {
    const int stg = (cur == 0) ? 2 : cur - 1;   // (t+2)%3, freed end of t-1
    const bool do_stage = (t + 2) < NT;
    const int kt2 = (t + 2) << 6;
    const unsigned short* Ab = &As[cur][0][0];
    const unsigned short* Bb = &Bs[cur][0][0];

    // ---- phase A: stage A0..A2 of tile t+2; read A-frags + B cols 0..31
    if (do_stage) {
      ASYNC_LD16(gA[0] + kt2, lA[0] + stg * 16384);
      ASYNC_LD16(gA[1] + kt2, lA[1] + stg * 16384);
      ASYNC_LD16(gA[2] + kt2, lA[2] + stg * 16384);
    }
    short8 af[4][2], bf2[2][2];
    #pragma unroll
    for (int mi = 0; mi < 4; mi++)
      #pragma unroll
      for (int k = 0; k < 2; k++)
        af[mi][k] = *(const short8*)(Ab + (wmr + mi*16 + lr) * 64 + (((k<<2) + lq) ^ r7) * 8);
    #pragma unroll
    for (int ni = 0; ni < 2; ni++)
      #pragma unroll
      for (int k = 0; k < 2; k++)
        bf2[ni][k] = *(const short8*)(Bb + (wnc + ni*16 + lr) * 64 + (((k<<2) + lq) ^ r7) * 8);
    __builtin_amdgcn_s_barrier();
    __builtin_amdgcn_s_setprio(1);
    #pragma unroll
    for (int mi = 0; mi < 4; mi++)
      #pragma unroll
      for (int ni = 0; ni < 2; ni++)
        #pragma unroll
        for (int k = 0; k < 2; k++)
          acc[mi][ni] = __builtin_amdgcn_mfma_f32_16x16x32_bf16(af[mi][k], bf2[ni][k], acc[mi][ni], 0, 0, 0);
    __builtin_amdgcn_s_setprio(0);
    __builtin_amdgcn_s_barrier();

    // ---- phase B: stage A3,B0,B1 of tile t+2; read B cols 32..63 (A reused)
    if (do_stage) {
      ASYNC_LD16(gA[3] + kt2, lA[3] + stg * 16384);
      ASYNC_LD16(gB[0] + kt2, lB[0] + stg * 8192);
      ASYNC_LD16(gB[1] + kt2, lB[1] + stg * 8192);
    }
    short8 bf3[2][2];
    #pragma unroll
    for (int ni = 0; ni < 2; ni++)
      #pragma unroll
      for (int k = 0; k < 2; k++)
        bf3[ni][k] = *(const short8*)(Bb + (wnc + (ni+2)*16 + lr) * 64 + (((k<<2) + lq) ^ r7) * 8);
    __builtin_amdgcn_s_barrier();
    __builtin_amdgcn_s_setprio(1);
    #pragma unroll
    for (int mi = 0; mi < 4; mi++)
      #pragma unroll
      for (int ni = 0; ni < 2; ni++)
        #pragma unroll
        for (int k = 0; k < 2; k++)
          acc[mi][ni+2] = __builtin_amdgcn_mfma_f32_16x16x32_bf16(af[mi][k], bf3[ni][k], acc[mi][ni+2], 0, 0, 0);
    __builtin_amdgcn_s_setprio(0);
    // boundary: guarantee tile t+1 landed; leave tile t+2's 6 loads in
    // flight (counted vmcnt — only the final tile drains to 0).
    if (t + 1 >= NT - 1) { asm volatile("s_waitcnt vmcnt(0)" ::: "memory"); }
    else                 { asm volatile("s_waitcnt vmcnt(6)" ::: "memory"); }
    __builtin_amdgcn_s_barrier();
    cur = (cur == 2) ? 0 : cur + 1;
  }

  #pragma unroll
  for (int mi = 0; mi < 4; mi++) {
    float s4[4];   // EPI3: per-row partial sums
    float iv[4];   // EPI4: per-row 1/rowsum
    if constexpr (EPI == 3) {
      #pragma unroll
      for (int r = 0; r < 4; r++) s4[r] = 0.f;
    }
    if constexpr (EPI == 4) {
      #pragma unroll
      for (int r = 0; r < 4; r++) {
        const int gm = row0 + wmr + mi * 16 + lq * 4 + r;
        iv[r] = 1.0f / f0[(long long)bz * 2048 + gm];
      }
    }
    #pragma unroll
    for (int ni = 0; ni < 4; ni++) {
      #pragma unroll
      for (int r = 0; r < 4; r++) {
        const int gm = row0 + wmr + mi * 16 + lq * 4 + r;
        const int gn = col0 + wnc + ni * 16 + lr;
        float v = acc[mi][ni][r];
        if constexpr (EPI == 0) {
          v += bias[gn];
          if (gn < 1024) {
            ((unsigned short*)f0)[(long long)gm * 1024 + gn] = f2u(sigmoidf_(v)); // u bf16
          } else if (gn < 2048) {
            b0[(long long)gm * 1024 + (gn - 1024)] = f2u(siluf_(v));    // r
          } else {
            const int z = gn - 2048;
            b1[(long long)gm * 128 + z] = f2u(siluf_(v) * gam[z] + bet[z]); // q
          }
        } else if constexpr (EPI == 1) {
          v += bias[gn];
          b0[(long long)gm * 128 + gn] = f2u(siluf_(v) * gam[gn] + bet[gn]); // k
        } else if constexpr (EPI == 2) {
          v += bias[gm];                                               // bias by e-row
          const int b = gn >> 11, s = gn & 2047;
          b0[((long long)b * 1024 + gm) * 2048 + s] = f2u(siluf_(v));  // v^T coalesced
        } else if constexpr (EPI == 3) {
          // unnormalized softmax numerator (logits ~1e-3: overflow-safe, no max)
          const float e = __expf(v * SCALING);
          b0[(long long)bz * 2048 * 2048 + (long long)gm * 2048 + gn] = f2u(e);
          s4[r] += e;
        } else if constexpr (EPI == 4) {
          const long long idx = ((long long)gm * 4 + bz) * 1024 + gn;  // (t,b,e)
          b0[idx] = f2u(v * iv[r] * u2f(rmul[idx]));                   // h*r
        } else { // EPI == 5
          const long long idx = (long long)gm * 1024 + gn;
          const float tv = tanhf(v + bias[gn]);
          const float qv = qin[idx];
          f0[idx] = qv + u2f(rmul[idx]) * (tv - qv);                   // final out
        }
      }
    }
    if constexpr (EPI == 3) {
      #pragma unroll
      for (int r = 0; r < 4; r++) {
        float s = s4[r];
        #pragma unroll
        for (int m2 = 8; m2 >= 1; m2 >>= 1) s += __shfl_xor(s, m2); // 16-lane group
        if (lr == 0) {
          const int gm = row0 + wmr + mi * 16 + lq * 4 + r;
          atomicAdd(f0 + (long long)bz * 2048 + gm, s);
        }
      }
    }
  }
}

// ---------------------------------------------------------------- launch
extern "C" void kernel_launch(void* const* d_in, const int* in_sizes, int n_in,
                              void* d_out, int out_size, void* d_ws, size_t ws_size,
                              hipStream_t stream)
{
  (void)in_sizes; (void)n_in; (void)out_size; (void)ws_size;
  const float* query = (const float*)d_in[0];
  const float* key   = (const float*)d_in[1];
  const float* Wq    = (const float*)d_in[2];
  const float* bq    = (const float*)d_in[3];
  const float* Wk    = (const float*)d_in[4];
  const float* bk    = (const float*)d_in[5];
  const float* Wv    = (const float*)d_in[6];
  const float* bv    = (const float*)d_in[7];
  const float* Wh    = (const float*)d_in[8];
  const float* bh    = (const float*)d_in[9];
  const float* gamma = (const float*)d_in[10];
  const float* beta  = (const float*)d_in[11];
  float* out = (float*)d_out;

  char* p = (char*)d_ws;
  auto take = [&](size_t bytes) -> char* {
    char* r = p; p += (bytes + 255) & ~(size_t)255; return r;
  };
  unsigned short* qbf = (unsigned short*)take(8192ULL * 1024 * 2); // query bf16 (T*B,E)
  unsigned short* kbr = (unsigned short*)take(8192ULL * 1024 * 2); // key bf16 [B][S][E]
  unsigned short* Wqb = (unsigned short*)take(2176ULL * 1024 * 2);
  unsigned short* Wkb = (unsigned short*)take(128ULL  * 1024 * 2);
  unsigned short* Wvb = (unsigned short*)take(1024ULL * 1024 * 2);
  unsigned short* Whb = (unsigned short*)take(1024ULL * 1024 * 2);
  unsigned short* ub  = (unsigned short*)take(8192ULL * 1024 * 2); // u gate bf16
  unsigned short* rbf = (unsigned short*)take(8192ULL * 1024 * 2); // r bf16
  unsigned short* qpj = (unsigned short*)take(8192ULL * 128 * 2);  // q (T,B,Z)
  unsigned short* kpj = (unsigned short*)take(8192ULL * 128 * 2);  // k [B][S][Z]
  unsigned short* vT  = (unsigned short*)take(4ULL * 1024 * 2048 * 2); // v^T [B][E][S]
  unsigned short* Pb  = (unsigned short*)take(4ULL * 2048 * 2048 * 2); // P~ [B][T][S]
  unsigned short* hrb = (unsigned short*)take(8192ULL * 1024 * 2); // h*r bf16
  float*          rs  = (float*)take(4ULL * 2048 * 4);             // rowsums [B][T]

  dim3 blk(256);
  dim3 gblk(512);
  cast_act<<<16384, blk, 0, stream>>>(query, key, qbf, kbr);
  cast_w<<<4352, blk, 0, stream>>>(Wq, Wk, Wv, Wh, Wqb, Wkb, Wvb, Whb);
  hipMemsetAsync(rs, 0, 4ULL * 2048 * 4, stream);

  // base = query @ Wq^T + bq -> u (sigmoid, bf16), r (silu), q (silu*g0+b0)
  gemm_bt<0><<<dim3(32, 17, 1), gblk, 0, stream>>>(qbf, 0, 1024, Wqb, 0, 1024, 1024,
      bq, gamma, beta, (float*)ub, rbf, qpj, nullptr, nullptr);
  // k[b][s][z] = silu(kbr @ Wk^T + bk)*g1+b1
  gemm_bt<1><<<dim3(32, 1, 1), gblk, 0, stream>>>(kbr, 0, 1024, Wkb, 0, 1024, 1024,
      bk, gamma + 128, beta + 128, nullptr, kpj, nullptr, nullptr, nullptr);
  // v^T[b][e][s] = silu(Wv @ kbr^T + bv)  (swapped orientation -> coalesced store)
  gemm_bt<2><<<dim3(4, 64, 1), gblk, 0, stream>>>(Wvb, 0, 1024, kbr, 0, 1024, 1024,
      bv, nullptr, nullptr, nullptr, vT, nullptr, nullptr, nullptr);
  // P~[b][t][s] = exp(scaling * q_b @ k_b^T), rowsums -> rs (atomic)
  gemm_bt<3><<<dim3(8, 16, 4), gblk, 0, stream>>>(qpj, 128, 512, kpj, 2048LL * 128, 128, 128,
      nullptr, nullptr, nullptr, rs, Pb, nullptr, nullptr, nullptr);
  // hr[t,b,e] = (P~_b @ vT_b^T)/rowsum * r
  gemm_bt<4><<<dim3(8, 8, 4), gblk, 0, stream>>>(Pb, 2048LL * 2048, 2048,
      vT, 1024LL * 2048, 2048, 2048,
      nullptr, nullptr, nullptr, rs, hrb, nullptr, rbf, nullptr);
  // out = query + u * (tanh(hr @ Wh^T + bh) - query)
  gemm_bt<5><<<dim3(32, 8, 1), gblk, 0, stream>>>(hrb, 0, 1024, Whb, 0, 1024, 1024,
      bh, nullptr, nullptr, out, nullptr, nullptr, ub, query);
}